// Round 4
// baseline (7282.909 us; speedup 1.0000x reference)
//
#include <hip/hip_runtime.h>
#include <cstdint>
#include <cstddef>

// Problem constants
#define NBATCH   8192
#define DFEAT    256
#define DCONV    128
#define NCLASS   5
#define NEDGE    500000
#define NUSERS   100000
#define BN_EPS   1e-3f
#define NBUCKET  128     // dst buckets of 64 rows each
#define BROWS    64

typedef unsigned short u16;
typedef short bf16x8_t __attribute__((ext_vector_type(8)));
typedef float f32x4_t  __attribute__((ext_vector_type(4)));

__device__ __forceinline__ u16 f2bf(float x) {
    unsigned u = __float_as_uint(x);
    u += 0x7FFF + ((u >> 16) & 1);
    return (u16)(u >> 16);
}
__device__ __forceinline__ float bf2f(u16 h) {
    return __uint_as_float(((unsigned)h) << 16);
}

// ============================================================================
// bf16 MFMA GEMM core: tile 64x64, block = 256 threads (4 waves), K-step 32.
// A row-major [M x K] bf16 (optionally row-gathered); BT row-major [N x K] bf16.
// LDS fragment-ordered -> all ds traffic conflict-free b128.
//   C/D: lane l, reg r -> row = (l>>4)*4 + r, col = l&15   (m89-verified)
// ============================================================================
__device__ __forceinline__ void mfma_tiles(
    const u16* __restrict__ A, int lda, const int* __restrict__ gather,
    const u16* __restrict__ BT, int K,
    int tileM, int tileN, u16* As, u16* Bs, f32x4_t acc[4])
{
    const int t    = threadIdx.x;
    const int rowi = t >> 2;
    const int kc   = t & 3;
    const int w    = t >> 6;
    const int lane = t & 63;

    int ar = gather ? gather[tileM + rowi] : (tileM + rowi);
    const u16* Ap = A  + (size_t)ar * lda + kc * 8;
    const u16* Bp = BT + (size_t)(tileN + rowi) * K + kc * 8;
    u16* Aw = As + (size_t)(((rowi >> 4) * 64) + (rowi & 15) + 16 * kc) * 8;
    u16* Bw = Bs + (size_t)(((rowi >> 4) * 64) + (rowi & 15) + 16 * kc) * 8;
    const u16* Ar = As + (size_t)(w * 64 + lane) * 8;

    for (int k0 = 0; k0 < K; k0 += 32) {
        __syncthreads();
        *(uint4*)Aw = *(const uint4*)(Ap + k0);
        *(uint4*)Bw = *(const uint4*)(Bp + k0);
        __syncthreads();
        bf16x8_t av = *(const bf16x8_t*)Ar;
        #pragma unroll
        for (int nb = 0; nb < 4; ++nb) {
            bf16x8_t bv = *(const bf16x8_t*)(Bs + (size_t)(nb * 64 + lane) * 8);
            acc[nb] = __builtin_amdgcn_mfma_f32_16x16x32_bf16(av, bv, acc[nb], 0, 0, 0);
        }
    }
}

__device__ __forceinline__ void epilogue(
    f32x4_t acc[4], int tileM, int tileN,
    const float* __restrict__ bias, const float* __restrict__ bn, int bn_ld,
    int relu, u16* __restrict__ out_bf, float* __restrict__ out_f32, int ldc)
{
    const int t = threadIdx.x, w = t >> 6, lane = t & 63;
    const int row0 = tileM + w * 16 + (lane >> 4) * 4;
    #pragma unroll
    for (int nb = 0; nb < 4; ++nb) {
        int col = tileN + nb * 16 + (lane & 15);
        float g = 1.f, be = 0.f, mu = 0.f, va = 1.f, bs = 0.f;
        if (bn)   { g = bn[col]; be = bn[bn_ld + col]; mu = bn[2 * bn_ld + col]; va = bn[3 * bn_ld + col]; }
        if (bias) bs = bias[col];
        #pragma unroll
        for (int r = 0; r < 4; ++r) {
            float x = acc[nb][r] + bs;
            if (bn)   x = g * (x - mu) * rsqrtf(va + BN_EPS) + be;
            if (relu) x = fmaxf(x, 0.f);
            size_t o = (size_t)(row0 + r) * ldc + col;
            if (out_bf) out_bf[o] = f2bf(x);
            else        out_f32[o] = x;
        }
    }
}

__global__ __launch_bounds__(256) void k_gemm_f(
    const u16* __restrict__ feat_bf, const int* __restrict__ idx,
    const u16* __restrict__ WT, const float* __restrict__ bias,
    const float* __restrict__ bn, u16* __restrict__ out)
{
    __shared__ __align__(16) u16 As[2048], Bs[2048];
    f32x4_t z = {0.f, 0.f, 0.f, 0.f};
    f32x4_t acc[4] = {z, z, z, z};
    int tileM = blockIdx.x * 64, tileN = blockIdx.y * 64;
    mfma_tiles(feat_bf, 256, idx, WT, 256, tileM, tileN, As, Bs, acc);
    epilogue(acc, tileM, tileN, bias, bn, 256, 1, out, nullptr, 256);
}

__global__ __launch_bounds__(256) void k_hproj(
    const u16* __restrict__ agg, const u16* __restrict__ WucT, const u16* __restrict__ WicT,
    const float* __restrict__ bn_hu, const float* __restrict__ bn_hi,
    u16* __restrict__ h_user, u16* __restrict__ h_item)
{
    __shared__ __align__(16) u16 As[2048], Bs[2048];
    f32x4_t z = {0.f, 0.f, 0.f, 0.f};
    f32x4_t acc[4] = {z, z, z, z};
    int cs = blockIdx.z, c = cs % NCLASS, side = cs / NCLASS;
    const u16* A  = agg + (size_t)cs * NBATCH * DFEAT;
    const u16* BT = (side ? WicT : WucT) + (size_t)c * DCONV * DFEAT;
    const float* bn = (side ? bn_hi : bn_hu) + c * DCONV;
    u16* out = (side ? h_item : h_user) + c * DCONV;
    int tileM = blockIdx.x * 64, tileN = blockIdx.y * 64;
    mfma_tiles(A, 256, nullptr, BT, 256, tileM, tileN, As, Bs, acc);
    epilogue(acc, tileM, tileN, nullptr, bn, NCLASS * DCONV, 1, out, nullptr, NCLASS * DCONV);
}

__global__ __launch_bounds__(256) void k_emb(
    const u16* __restrict__ fbf, const u16* __restrict__ hbf,
    const u16* __restrict__ W2fT, const u16* __restrict__ W2hT,
    u16* __restrict__ emb)
{
    __shared__ __align__(16) u16 As[2048], Bs[2048];
    f32x4_t z = {0.f, 0.f, 0.f, 0.f};
    f32x4_t acc[4] = {z, z, z, z};
    int tileM = blockIdx.x * 64, tileN = blockIdx.y * 64;
    mfma_tiles(fbf, 256, nullptr, W2fT, 256, tileM, tileN, As, Bs, acc);
    mfma_tiles(hbf, NCLASS * DCONV, nullptr, W2hT, NCLASS * DCONV, tileM, tileN, As, Bs, acc);
    epilogue(acc, tileM, tileN, nullptr, nullptr, 0, 1, emb, nullptr, 256);
}

__global__ __launch_bounds__(256) void k_dec(
    const u16* __restrict__ emb, const u16* __restrict__ WdecT,
    float* __restrict__ t0, float* __restrict__ t1)
{
    __shared__ __align__(16) u16 As[2048], Bs[2048];
    f32x4_t z = {0.f, 0.f, 0.f, 0.f};
    f32x4_t acc[4] = {z, z, z, z};
    int zi = blockIdx.z;
    const u16* BT = WdecT + (size_t)zi * 256 * 256;
    float* out = zi ? t1 : t0;
    int tileM = blockIdx.x * 64, tileN = blockIdx.y * 64;
    mfma_tiles(emb, 256, nullptr, BT, 256, tileM, tileN, As, Bs, acc);
    epilogue(acc, tileM, tileN, nullptr, nullptr, 0, 0, nullptr, out, 256);
}

// ============================================================================
// prep conversions
// ============================================================================
__global__ __launch_bounds__(256) void cvt_feat(
    const float* __restrict__ uf, const float* __restrict__ itf,
    u16* __restrict__ ubf, u16* __restrict__ ibf)
{
    const size_t n4 = (size_t)NUSERS * DFEAT / 4;
    for (size_t i = (size_t)blockIdx.x * 256 + threadIdx.x; i < 2 * n4;
         i += (size_t)gridDim.x * 256) {
        bool u = i < n4;
        size_t j = u ? i : i - n4;
        float4 v = u ? ((const float4*)uf)[j] : ((const float4*)itf)[j];
        ushort4 o;
        o.x = f2bf(v.x); o.y = f2bf(v.y); o.z = f2bf(v.z); o.w = f2bf(v.w);
        ((ushort4*)(u ? ubf : ibf))[j] = o;
    }
}

#define OFF_WFU   0
#define OFF_WFI   65536
#define OFF_WUC   131072
#define OFF_WIC   294912
#define OFF_W2FU  458752
#define OFF_W2HU  524288
#define OFF_W2FI  688128
#define OFF_W2HI  753664
#define OFF_WDEC  917504

__global__ __launch_bounds__(256) void cvt_wt(
    const float* __restrict__ Wfu, const float* __restrict__ Wfi,
    const float* __restrict__ Wuc, const float* __restrict__ Wic,
    const float* __restrict__ W2fu, const float* __restrict__ W2hu,
    const float* __restrict__ W2fi, const float* __restrict__ W2hi,
    const float* __restrict__ Wdec, u16* __restrict__ wT)
{
    const float* in; u16* out; int K, N, B;
    switch (blockIdx.y) {
        case 0: in = Wfu;  out = wT + OFF_WFU;  K = 256; N = 256; B = 1; break;
        case 1: in = Wfi;  out = wT + OFF_WFI;  K = 256; N = 256; B = 1; break;
        case 2: in = Wuc;  out = wT + OFF_WUC;  K = 256; N = 128; B = 5; break;
        case 3: in = Wic;  out = wT + OFF_WIC;  K = 256; N = 128; B = 5; break;
        case 4: in = W2fu; out = wT + OFF_W2FU; K = 256; N = 256; B = 1; break;
        case 5: in = W2hu; out = wT + OFF_W2HU; K = 640; N = 256; B = 1; break;
        case 6: in = W2fi; out = wT + OFF_W2FI; K = 256; N = 256; B = 1; break;
        case 7: in = W2hi; out = wT + OFF_W2HI; K = 640; N = 256; B = 1; break;
        default: in = Wdec; out = wT + OFF_WDEC; K = 256; N = 256; B = 2; break;
    }
    int total = B * K * N;
    for (int idx = blockIdx.x * 256 + threadIdx.x; idx < total; idx += gridDim.x * 256) {
        int b = idx / (K * N);
        int r = idx - b * K * N;
        int n = r / K;
        int k = r - n * K;
        out[idx] = f2bf(in[(size_t)(b * K + k) * N + n]);
    }
}

// ============================================================================
// Bucketed graph aggregation.
// Buckets: dst>>6 (128 buckets x 64 rows per class-side).
// partition: edge (src,w,dstlow) packed to uint2, appended to its bucket run
//            via a global bucket cursor. 1280 sequential write frontiers ->
//            ~1x line-level write amplification (vs 8x for per-dst scatter).
// spmm_bucket: one block per (cs,bucket); 64x256 fp32 accumulator in 64KB LDS
//              (swizzled col 4l+j -> slot j*64+l: ds_add bank = lane%32, free).
// ============================================================================
__global__ __launch_bounds__(256) void hist_bucket(
    const int* __restrict__ u_dst, const int* __restrict__ i_dst,
    int* __restrict__ bcounts)
{
    __shared__ int h[NBUCKET];
    int cs = blockIdx.y;
    const int* dstp = (cs < NCLASS) ? (u_dst + (size_t)cs * NEDGE)
                                    : (i_dst + (size_t)(cs - NCLASS) * NEDGE);
    for (int i = threadIdx.x; i < NBUCKET; i += 256) h[i] = 0;
    __syncthreads();
    for (int e = blockIdx.x * 256 + threadIdx.x; e < NEDGE; e += gridDim.x * 256)
        atomicAdd(&h[dstp[e] >> 6], 1);
    __syncthreads();
    for (int i = threadIdx.x; i < NBUCKET; i += 256)
        atomicAdd(&bcounts[cs * NBUCKET + i], h[i]);
}

// one block per class-side: exclusive scan of 128 bucket counts (+ sentinel)
__global__ __launch_bounds__(NBUCKET) void scan_bucket(
    const int* __restrict__ bcounts, int* __restrict__ boff, int* __restrict__ bcur)
{
    __shared__ int s[NBUCKET];
    int cs = blockIdx.x, t = threadIdx.x;
    s[t] = bcounts[cs * NBUCKET + t];
    __syncthreads();
    int incl = s[t];
    for (int ofs = 1; ofs < NBUCKET; ofs <<= 1) {
        int v = (t >= ofs) ? s[t - ofs] : 0;
        __syncthreads();
        s[t] += v;
        __syncthreads();
    }
    int excl = s[t] - incl;
    boff[cs * (NBUCKET + 1) + t] = excl;
    bcur[cs * NBUCKET + t]       = excl;
    if (t == NBUCKET - 1) boff[cs * (NBUCKET + 1) + NBUCKET] = NEDGE;
}

__global__ __launch_bounds__(256) void partition_kernel(
    const int* __restrict__ u_src, const int* __restrict__ u_dst, const float* __restrict__ u_w,
    const int* __restrict__ i_src, const int* __restrict__ i_dst, const float* __restrict__ i_w,
    int* __restrict__ bcur, uint2* __restrict__ part)
{
    int cs = blockIdx.y;
    const int* srcp; const int* dstp; const float* wp;
    if (cs < NCLASS) {
        srcp = u_src + (size_t)cs * NEDGE;
        dstp = u_dst + (size_t)cs * NEDGE;
        wp   = u_w   + (size_t)cs * NEDGE;
    } else {
        int c = cs - NCLASS;
        srcp = i_src + (size_t)c * NEDGE;
        dstp = i_dst + (size_t)c * NEDGE;
        wp   = i_w   + (size_t)c * NEDGE;
    }
    int*   cur = bcur + cs * NBUCKET;
    uint2* out = part + (size_t)cs * NEDGE;
    for (int e = blockIdx.x * 256 + threadIdx.x; e < NEDGE; e += gridDim.x * 256) {
        int dst = dstp[e];
        int b   = dst >> 6;
        unsigned low = (unsigned)(dst & 63);
        int pos = atomicAdd(&cur[b], 1);
        out[pos] = make_uint2((unsigned)srcp[e] | (low << 24), __float_as_uint(wp[e]));
    }
}

__global__ __launch_bounds__(256) void spmm_bucket(
    const u16* __restrict__ item_bf, const u16* __restrict__ user_bf,
    const uint2* __restrict__ part, const int* __restrict__ boff,
    u16* __restrict__ agg)
{
    __shared__ float acc[BROWS * 256];   // 64 KB, swizzled: (low, col=4q+j) -> low*256 + j*64 + q
    int b  = blockIdx.x;
    int cs = blockIdx.y;
    const u16* feat = (cs < NCLASS) ? item_bf : user_bf;
    int lo = boff[cs * (NBUCKET + 1) + b];
    int hi = boff[cs * (NBUCKET + 1) + b + 1];

    for (int i = threadIdx.x; i < BROWS * 256; i += 256) acc[i] = 0.f;
    __syncthreads();

    int wave = threadIdx.x >> 6;
    int lane = threadIdx.x & 63;
    const uint2* ew = part + (size_t)cs * NEDGE;

    int e = lo + wave;
    for (; e + 4 < hi; e += 8) {
        uint2 p0 = ew[e], p1 = ew[e + 4];
        int   s0 = p0.x & 0xFFFFFF,  s1 = p1.x & 0xFFFFFF;
        int   l0 = p0.x >> 24,       l1 = p1.x >> 24;
        float w0 = __uint_as_float(p0.y), w1 = __uint_as_float(p1.y);
        ushort4 v0 = *(const ushort4*)&feat[(size_t)s0 * DFEAT + lane * 4];
        ushort4 v1 = *(const ushort4*)&feat[(size_t)s1 * DFEAT + lane * 4];
        float* a0 = acc + l0 * 256;
        float* a1 = acc + l1 * 256;
        atomicAdd(a0 +       lane, w0 * bf2f(v0.x));
        atomicAdd(a0 +  64 + lane, w0 * bf2f(v0.y));
        atomicAdd(a0 + 128 + lane, w0 * bf2f(v0.z));
        atomicAdd(a0 + 192 + lane, w0 * bf2f(v0.w));
        atomicAdd(a1 +       lane, w1 * bf2f(v1.x));
        atomicAdd(a1 +  64 + lane, w1 * bf2f(v1.y));
        atomicAdd(a1 + 128 + lane, w1 * bf2f(v1.z));
        atomicAdd(a1 + 192 + lane, w1 * bf2f(v1.w));
    }
    for (; e < hi; e += 4) {
        uint2 p0 = ew[e];
        int   s0 = p0.x & 0xFFFFFF;
        int   l0 = p0.x >> 24;
        float w0 = __uint_as_float(p0.y);
        ushort4 v0 = *(const ushort4*)&feat[(size_t)s0 * DFEAT + lane * 4];
        float* a0 = acc + l0 * 256;
        atomicAdd(a0 +       lane, w0 * bf2f(v0.x));
        atomicAdd(a0 +  64 + lane, w0 * bf2f(v0.y));
        atomicAdd(a0 + 128 + lane, w0 * bf2f(v0.z));
        atomicAdd(a0 + 192 + lane, w0 * bf2f(v0.w));
    }
    __syncthreads();

    // writeback: un-swizzle, convert to bf16, coalesced ushort4 stores
    int rowbase = cs * NBATCH + b * BROWS;
    for (int i = threadIdx.x; i < BROWS * 64; i += 256) {
        int low = i >> 6, q = i & 63;
        const float* a = acc + low * 256;
        ushort4 o;
        o.x = f2bf(a[      q]);
        o.y = f2bf(a[ 64 + q]);
        o.z = f2bf(a[128 + q]);
        o.w = f2bf(a[192 + q]);
        *(ushort4*)&agg[((size_t)(rowbase + low)) * 256 + q * 4] = o;
    }
}

// ============================================================================
// decoder stage 2
// ============================================================================
__global__ __launch_bounds__(256) void decoder_kernel(
    const float* __restrict__ t0, const float* __restrict__ t1,
    const u16* __restrict__ item_emb, const float* __restrict__ Wcomb,
    float* __restrict__ out)
{
    int wave = threadIdx.x >> 6;
    int lane = threadIdx.x & 63;
    int b = blockIdx.x * 4 + wave;
    const u16*   ie = item_emb + (size_t)b * 256;
    const float* p0 = t0 + (size_t)b * 256;
    const float* p1 = t1 + (size_t)b * 256;
    float s0 = 0.f, s1 = 0.f;
    #pragma unroll
    for (int j = lane; j < 256; j += 64) {
        float v = bf2f(ie[j]);
        s0 += p0[j] * v;
        s1 += p1[j] * v;
    }
    #pragma unroll
    for (int o = 32; o > 0; o >>= 1) {
        s0 += __shfl_down(s0, o);
        s1 += __shfl_down(s1, o);
    }
    if (lane == 0) {
        #pragma unroll
        for (int r = 0; r < NCLASS; ++r)
            out[b * NCLASS + r] = Wcomb[r * 2 + 0] * s0 + Wcomb[r * 2 + 1] * s1;
    }
}

// ============================================================================
// launch
// ============================================================================
extern "C" void kernel_launch(void* const* d_in, const int* in_sizes, int n_in,
                              void* d_out, int out_size, void* d_ws, size_t ws_size,
                              hipStream_t stream)
{
    const float* user_feat = (const float*)d_in[0];
    const float* item_feat = (const float*)d_in[1];
    const int*   user_idx  = (const int*)  d_in[2];
    const int*   item_idx  = (const int*)  d_in[3];
    const int*   u_src     = (const int*)  d_in[4];
    const int*   u_dst     = (const int*)  d_in[5];
    const float* u_w       = (const float*)d_in[6];
    const int*   i_src     = (const int*)  d_in[7];
    const int*   i_dst     = (const int*)  d_in[8];
    const float* i_w       = (const float*)d_in[9];
    const float* W_fu      = (const float*)d_in[10];
    const float* b_fu      = (const float*)d_in[11];
    const float* W_fi      = (const float*)d_in[12];
    const float* b_fi      = (const float*)d_in[13];
    const float* W_uc      = (const float*)d_in[14];
    const float* W_ic      = (const float*)d_in[15];
    const float* bn_fu     = (const float*)d_in[16];
    const float* bn_hu     = (const float*)d_in[17];
    const float* bn_fi     = (const float*)d_in[18];
    const float* bn_hi     = (const float*)d_in[19];
    const float* W2_fu     = (const float*)d_in[20];
    const float* W2_hu     = (const float*)d_in[21];
    const float* W2_fi     = (const float*)d_in[22];
    const float* W2_hi     = (const float*)d_in[23];
    const float* Wdec      = (const float*)d_in[24];
    const float* Wcomb     = (const float*)d_in[25];
    float* out = (float*)d_out;

    // ---- workspace layout --------------------------------------------------
    char* ws = (char*)d_ws;
    int*   bcounts    = (int*)  (ws + 0);            // 10*128 i32
    int*   boff       = (int*)  (ws + 8192);         // 10*129 i32
    int*   bcur       = (int*)  (ws + 16384);        // 10*128 i32
    uint2* part_ew    = (uint2*)(ws + 983040);       // 40 MB (dead after spmm)
    u16*   user_bf    = (u16*)  (ws + 40983040);     // 51.2 MB
    u16*   item_bf    = (u16*)  (ws + 92183040);     // 51.2 MB
    u16*   agg_bf     = (u16*)  (ws + 143383040);    // 41.9 MB (dead after hproj)
    u16*   wT         = (u16*)  (ws + 185326080);    // 2.1 MB
    // overlays on part region (live f-gemm..emb, after spmm):
    u16*   f_user_bf  = (u16*)  (ws + 983040);
    u16*   f_item_bf  = (u16*)  (ws + 5177344);
    u16*   h_user_bf  = (u16*)  (ws + 9371648);
    u16*   h_item_bf  = (u16*)  (ws + 19857408);
    // overlays on agg region (live emb..decoder, after hproj):
    float* t0         = (float*)(ws + 143383040);
    float* t1         = (float*)(ws + 151771648);
    u16*   user_emb   = (u16*)  (ws + 160160256);
    u16*   item_emb   = (u16*)  (ws + 164354560);

    // ---- 1. bucket CSR build ----------------------------------------------
    hipMemsetAsync(bcounts, 0, 10 * NBUCKET * sizeof(int), stream);
    hist_bucket<<<dim3(64, 10), 256, 0, stream>>>(u_dst, i_dst, bcounts);
    scan_bucket<<<10, NBUCKET, 0, stream>>>(bcounts, boff, bcur);
    partition_kernel<<<dim3(128, 10), 256, 0, stream>>>(
        u_src, u_dst, u_w, i_src, i_dst, i_w, bcur, part_ew);

    // ---- 2. prep conversions ----------------------------------------------
    cvt_feat<<<4096, 256, 0, stream>>>(user_feat, item_feat, user_bf, item_bf);
    cvt_wt<<<dim3(160, 9), 256, 0, stream>>>(W_fu, W_fi, W_uc, W_ic,
                                             W2_fu, W2_hu, W2_fi, W2_hi, Wdec, wT);

    // ---- 3. bucketed SpMM aggregation -------------------------------------
    spmm_bucket<<<dim3(NBUCKET, 10), 256, 0, stream>>>(
        item_bf, user_bf, part_ew, boff, agg_bf);

    // ---- 4. f path ---------------------------------------------------------
    k_gemm_f<<<dim3(128, 4), 256, 0, stream>>>(user_bf, user_idx, wT + OFF_WFU,
                                               b_fu, bn_fu, f_user_bf);
    k_gemm_f<<<dim3(128, 4), 256, 0, stream>>>(item_bf, item_idx, wT + OFF_WFI,
                                               b_fi, bn_fi, f_item_bf);

    // ---- 5. h projection ---------------------------------------------------
    k_hproj<<<dim3(128, 2, 10), 256, 0, stream>>>(agg_bf, wT + OFF_WUC, wT + OFF_WIC,
                                                  bn_hu, bn_hi, h_user_bf, h_item_bf);

    // ---- 6. embeddings ------------------------------------------------------
    k_emb<<<dim3(128, 4), 256, 0, stream>>>(f_user_bf, h_user_bf,
                                            wT + OFF_W2FU, wT + OFF_W2HU, user_emb);
    k_emb<<<dim3(128, 4), 256, 0, stream>>>(f_item_bf, h_item_bf,
                                            wT + OFF_W2FI, wT + OFF_W2HI, item_emb);

    // ---- 7. decoder ---------------------------------------------------------
    k_dec<<<dim3(128, 4, 2), 256, 0, stream>>>(user_emb, wT + OFF_WDEC, t0, t1);
    decoder_kernel<<<NBATCH / 4, 256, 0, stream>>>(t0, t1, item_emb, Wcomb, out);
}

// Round 5
// 2316.394 us; speedup vs baseline: 3.1441x; 3.1441x over previous
//
#include <hip/hip_runtime.h>
#include <cstdint>
#include <cstddef>

// Problem constants
#define NBATCH   8192
#define DFEAT    256
#define DCONV    128
#define NCLASS   5
#define NEDGE    500000
#define NUSERS   100000
#define BN_EPS   1e-3f
#define NBUCKET  128     // dst buckets of 64 rows each
#define BROWS    64

typedef unsigned short u16;
typedef short bf16x8_t __attribute__((ext_vector_type(8)));
typedef float f32x4_t  __attribute__((ext_vector_type(4)));

__device__ __forceinline__ u16 f2bf(float x) {
    unsigned u = __float_as_uint(x);
    u += 0x7FFF + ((u >> 16) & 1);
    return (u16)(u >> 16);
}
__device__ __forceinline__ float bf2f(u16 h) {
    return __uint_as_float(((unsigned)h) << 16);
}

// ============================================================================
// bf16 MFMA GEMM core: tile 64x64, block = 256 threads (4 waves), K-step 32.
// A row-major [M x K] bf16 (optionally row-gathered); BT row-major [N x K] bf16.
// LDS fragment-ordered -> all ds traffic conflict-free b128.
//   C/D: lane l, reg r -> row = (l>>4)*4 + r, col = l&15   (m89-verified)
// ============================================================================
__device__ __forceinline__ void mfma_tiles(
    const u16* __restrict__ A, int lda, const int* __restrict__ gather,
    const u16* __restrict__ BT, int K,
    int tileM, int tileN, u16* As, u16* Bs, f32x4_t acc[4])
{
    const int t    = threadIdx.x;
    const int rowi = t >> 2;
    const int kc   = t & 3;
    const int w    = t >> 6;
    const int lane = t & 63;

    int ar = gather ? gather[tileM + rowi] : (tileM + rowi);
    const u16* Ap = A  + (size_t)ar * lda + kc * 8;
    const u16* Bp = BT + (size_t)(tileN + rowi) * K + kc * 8;
    u16* Aw = As + (size_t)(((rowi >> 4) * 64) + (rowi & 15) + 16 * kc) * 8;
    u16* Bw = Bs + (size_t)(((rowi >> 4) * 64) + (rowi & 15) + 16 * kc) * 8;
    const u16* Ar = As + (size_t)(w * 64 + lane) * 8;

    for (int k0 = 0; k0 < K; k0 += 32) {
        __syncthreads();
        *(uint4*)Aw = *(const uint4*)(Ap + k0);
        *(uint4*)Bw = *(const uint4*)(Bp + k0);
        __syncthreads();
        bf16x8_t av = *(const bf16x8_t*)Ar;
        #pragma unroll
        for (int nb = 0; nb < 4; ++nb) {
            bf16x8_t bv = *(const bf16x8_t*)(Bs + (size_t)(nb * 64 + lane) * 8);
            acc[nb] = __builtin_amdgcn_mfma_f32_16x16x32_bf16(av, bv, acc[nb], 0, 0, 0);
        }
    }
}

__device__ __forceinline__ void epilogue(
    f32x4_t acc[4], int tileM, int tileN,
    const float* __restrict__ bias, const float* __restrict__ bn, int bn_ld,
    int relu, u16* __restrict__ out_bf, float* __restrict__ out_f32, int ldc)
{
    const int t = threadIdx.x, w = t >> 6, lane = t & 63;
    const int row0 = tileM + w * 16 + (lane >> 4) * 4;
    #pragma unroll
    for (int nb = 0; nb < 4; ++nb) {
        int col = tileN + nb * 16 + (lane & 15);
        float g = 1.f, be = 0.f, mu = 0.f, va = 1.f, bs = 0.f;
        if (bn)   { g = bn[col]; be = bn[bn_ld + col]; mu = bn[2 * bn_ld + col]; va = bn[3 * bn_ld + col]; }
        if (bias) bs = bias[col];
        #pragma unroll
        for (int r = 0; r < 4; ++r) {
            float x = acc[nb][r] + bs;
            if (bn)   x = g * (x - mu) * rsqrtf(va + BN_EPS) + be;
            if (relu) x = fmaxf(x, 0.f);
            size_t o = (size_t)(row0 + r) * ldc + col;
            if (out_bf) out_bf[o] = f2bf(x);
            else        out_f32[o] = x;
        }
    }
}

__global__ __launch_bounds__(256) void k_gemm_f(
    const u16* __restrict__ feat_bf, const int* __restrict__ idx,
    const u16* __restrict__ WT, const float* __restrict__ bias,
    const float* __restrict__ bn, u16* __restrict__ out)
{
    __shared__ __align__(16) u16 As[2048], Bs[2048];
    f32x4_t z = {0.f, 0.f, 0.f, 0.f};
    f32x4_t acc[4] = {z, z, z, z};
    int tileM = blockIdx.x * 64, tileN = blockIdx.y * 64;
    mfma_tiles(feat_bf, 256, idx, WT, 256, tileM, tileN, As, Bs, acc);
    epilogue(acc, tileM, tileN, bias, bn, 256, 1, out, nullptr, 256);
}

__global__ __launch_bounds__(256) void k_hproj(
    const u16* __restrict__ agg, const u16* __restrict__ WucT, const u16* __restrict__ WicT,
    const float* __restrict__ bn_hu, const float* __restrict__ bn_hi,
    u16* __restrict__ h_user, u16* __restrict__ h_item)
{
    __shared__ __align__(16) u16 As[2048], Bs[2048];
    f32x4_t z = {0.f, 0.f, 0.f, 0.f};
    f32x4_t acc[4] = {z, z, z, z};
    int cs = blockIdx.z, c = cs % NCLASS, side = cs / NCLASS;
    const u16* A  = agg + (size_t)cs * NBATCH * DFEAT;
    const u16* BT = (side ? WicT : WucT) + (size_t)c * DCONV * DFEAT;
    const float* bn = (side ? bn_hi : bn_hu) + c * DCONV;
    u16* out = (side ? h_item : h_user) + c * DCONV;
    int tileM = blockIdx.x * 64, tileN = blockIdx.y * 64;
    mfma_tiles(A, 256, nullptr, BT, 256, tileM, tileN, As, Bs, acc);
    epilogue(acc, tileM, tileN, nullptr, bn, NCLASS * DCONV, 1, out, nullptr, NCLASS * DCONV);
}

__global__ __launch_bounds__(256) void k_emb(
    const u16* __restrict__ fbf, const u16* __restrict__ hbf,
    const u16* __restrict__ W2fT, const u16* __restrict__ W2hT,
    u16* __restrict__ emb)
{
    __shared__ __align__(16) u16 As[2048], Bs[2048];
    f32x4_t z = {0.f, 0.f, 0.f, 0.f};
    f32x4_t acc[4] = {z, z, z, z};
    int tileM = blockIdx.x * 64, tileN = blockIdx.y * 64;
    mfma_tiles(fbf, 256, nullptr, W2fT, 256, tileM, tileN, As, Bs, acc);
    mfma_tiles(hbf, NCLASS * DCONV, nullptr, W2hT, NCLASS * DCONV, tileM, tileN, As, Bs, acc);
    epilogue(acc, tileM, tileN, nullptr, nullptr, 0, 1, emb, nullptr, 256);
}

__global__ __launch_bounds__(256) void k_dec(
    const u16* __restrict__ emb, const u16* __restrict__ WdecT,
    float* __restrict__ t0, float* __restrict__ t1)
{
    __shared__ __align__(16) u16 As[2048], Bs[2048];
    f32x4_t z = {0.f, 0.f, 0.f, 0.f};
    f32x4_t acc[4] = {z, z, z, z};
    int zi = blockIdx.z;
    const u16* BT = WdecT + (size_t)zi * 256 * 256;
    float* out = zi ? t1 : t0;
    int tileM = blockIdx.x * 64, tileN = blockIdx.y * 64;
    mfma_tiles(emb, 256, nullptr, BT, 256, tileM, tileN, As, Bs, acc);
    epilogue(acc, tileM, tileN, nullptr, nullptr, 0, 0, nullptr, out, 256);
}

// ============================================================================
// prep conversions
// ============================================================================
__global__ __launch_bounds__(256) void cvt_feat(
    const float* __restrict__ uf, const float* __restrict__ itf,
    u16* __restrict__ ubf, u16* __restrict__ ibf)
{
    const size_t n4 = (size_t)NUSERS * DFEAT / 4;
    for (size_t i = (size_t)blockIdx.x * 256 + threadIdx.x; i < 2 * n4;
         i += (size_t)gridDim.x * 256) {
        bool u = i < n4;
        size_t j = u ? i : i - n4;
        float4 v = u ? ((const float4*)uf)[j] : ((const float4*)itf)[j];
        ushort4 o;
        o.x = f2bf(v.x); o.y = f2bf(v.y); o.z = f2bf(v.z); o.w = f2bf(v.w);
        ((ushort4*)(u ? ubf : ibf))[j] = o;
    }
}

#define OFF_WFU   0
#define OFF_WFI   65536
#define OFF_WUC   131072
#define OFF_WIC   294912
#define OFF_W2FU  458752
#define OFF_W2HU  524288
#define OFF_W2FI  688128
#define OFF_W2HI  753664
#define OFF_WDEC  917504

__global__ __launch_bounds__(256) void cvt_wt(
    const float* __restrict__ Wfu, const float* __restrict__ Wfi,
    const float* __restrict__ Wuc, const float* __restrict__ Wic,
    const float* __restrict__ W2fu, const float* __restrict__ W2hu,
    const float* __restrict__ W2fi, const float* __restrict__ W2hi,
    const float* __restrict__ Wdec, u16* __restrict__ wT)
{
    const float* in; u16* out; int K, N, B;
    switch (blockIdx.y) {
        case 0: in = Wfu;  out = wT + OFF_WFU;  K = 256; N = 256; B = 1; break;
        case 1: in = Wfi;  out = wT + OFF_WFI;  K = 256; N = 256; B = 1; break;
        case 2: in = Wuc;  out = wT + OFF_WUC;  K = 256; N = 128; B = 5; break;
        case 3: in = Wic;  out = wT + OFF_WIC;  K = 256; N = 128; B = 5; break;
        case 4: in = W2fu; out = wT + OFF_W2FU; K = 256; N = 256; B = 1; break;
        case 5: in = W2hu; out = wT + OFF_W2HU; K = 640; N = 256; B = 1; break;
        case 6: in = W2fi; out = wT + OFF_W2FI; K = 256; N = 256; B = 1; break;
        case 7: in = W2hi; out = wT + OFF_W2HI; K = 640; N = 256; B = 1; break;
        default: in = Wdec; out = wT + OFF_WDEC; K = 256; N = 256; B = 2; break;
    }
    int total = B * K * N;
    for (int idx = blockIdx.x * 256 + threadIdx.x; idx < total; idx += gridDim.x * 256) {
        int b = idx / (K * N);
        int r = idx - b * K * N;
        int n = r / K;
        int k = r - n * K;
        out[idx] = f2bf(in[(size_t)(b * K + k) * N + n]);
    }
}

// ============================================================================
// Bucketed graph aggregation.
// Buckets: dst>>6 (128 buckets x 64 rows per class-side).
// partition: edge (src | low6<<24, w) appended to its bucket run via global
//            int cursor -> 1280 sequential write frontiers, ~1x write amp.
// spmm_scan: block (bucket, cs) of 512 thr (8 waves). Wave w owns the 8 rows
//            with low6 in [8w, 8w+8) and accumulates them in REGISTERS.
//            Each wave scans the whole bucket edge list (wave-uniform loads,
//            ~1/8 hit rate, wave-uniform branch), gathers the 512B feature
//            row coalesced on hit, FMAs via a wave-uniform 8-way switch.
//            No LDS, no float atomics (LDS float atomicAdd = CAS loop on
//            gfx950 without unsafe-fp-atomics -- R4's 6.4ms lesson).
// ============================================================================
__global__ __launch_bounds__(256) void hist_bucket(
    const int* __restrict__ u_dst, const int* __restrict__ i_dst,
    int* __restrict__ bcounts)
{
    __shared__ int h[NBUCKET];
    int cs = blockIdx.y;
    const int* dstp = (cs < NCLASS) ? (u_dst + (size_t)cs * NEDGE)
                                    : (i_dst + (size_t)(cs - NCLASS) * NEDGE);
    for (int i = threadIdx.x; i < NBUCKET; i += 256) h[i] = 0;
    __syncthreads();
    for (int e = blockIdx.x * 256 + threadIdx.x; e < NEDGE; e += gridDim.x * 256)
        atomicAdd(&h[dstp[e] >> 6], 1);          // int LDS atomic: native ds_add
    __syncthreads();
    for (int i = threadIdx.x; i < NBUCKET; i += 256)
        atomicAdd(&bcounts[cs * NBUCKET + i], h[i]);
}

__global__ __launch_bounds__(NBUCKET) void scan_bucket(
    const int* __restrict__ bcounts, int* __restrict__ boff, int* __restrict__ bcur)
{
    __shared__ int s[NBUCKET];
    int cs = blockIdx.x, t = threadIdx.x;
    s[t] = bcounts[cs * NBUCKET + t];
    __syncthreads();
    int incl = s[t];
    for (int ofs = 1; ofs < NBUCKET; ofs <<= 1) {
        int v = (t >= ofs) ? s[t - ofs] : 0;
        __syncthreads();
        s[t] += v;
        __syncthreads();
    }
    int excl = s[t] - incl;
    boff[cs * (NBUCKET + 1) + t] = excl;
    bcur[cs * NBUCKET + t]       = excl;
    if (t == NBUCKET - 1) boff[cs * (NBUCKET + 1) + NBUCKET] = NEDGE;
}

__global__ __launch_bounds__(256) void partition_kernel(
    const int* __restrict__ u_src, const int* __restrict__ u_dst, const float* __restrict__ u_w,
    const int* __restrict__ i_src, const int* __restrict__ i_dst, const float* __restrict__ i_w,
    int* __restrict__ bcur, uint2* __restrict__ part)
{
    int cs = blockIdx.y;
    const int* srcp; const int* dstp; const float* wp;
    if (cs < NCLASS) {
        srcp = u_src + (size_t)cs * NEDGE;
        dstp = u_dst + (size_t)cs * NEDGE;
        wp   = u_w   + (size_t)cs * NEDGE;
    } else {
        int c = cs - NCLASS;
        srcp = i_src + (size_t)c * NEDGE;
        dstp = i_dst + (size_t)c * NEDGE;
        wp   = i_w   + (size_t)c * NEDGE;
    }
    int*   cur = bcur + cs * NBUCKET;
    uint2* out = part + (size_t)cs * NEDGE;
    for (int e = blockIdx.x * 256 + threadIdx.x; e < NEDGE; e += gridDim.x * 256) {
        int dst = dstp[e];
        int b   = dst >> 6;
        unsigned low = (unsigned)(dst & 63);
        int pos = atomicAdd(&cur[b], 1);
        out[pos] = make_uint2((unsigned)srcp[e] | (low << 24), __float_as_uint(wp[e]));
    }
}

__global__ __launch_bounds__(512) void spmm_scan(
    const u16* __restrict__ item_bf, const u16* __restrict__ user_bf,
    const uint2* __restrict__ part, const int* __restrict__ boff,
    u16* __restrict__ agg)
{
    int b  = blockIdx.x;
    int cs = blockIdx.y;
    const u16* feat = (cs < NCLASS) ? item_bf : user_bf;
    int lo = boff[cs * (NBUCKET + 1) + b];
    int hi = boff[cs * (NBUCKET + 1) + b + 1];
    int wave = threadIdx.x >> 6;      // 0..7: owns rows low6 in [8*wave, 8*wave+8)
    int lane = threadIdx.x & 63;

    float acc[8][4];
    #pragma unroll
    for (int r = 0; r < 8; ++r)
        #pragma unroll
        for (int j = 0; j < 4; ++j) acc[r][j] = 0.f;

    const uint2* ew = part + (size_t)cs * NEDGE;

    #pragma unroll 4
    for (int e = lo; e < hi; ++e) {
        uint2 p = ew[e];                         // wave-uniform address
        int low = (int)(p.x >> 24);
        if ((low >> 3) != wave) continue;        // wave-uniform branch
        unsigned src = p.x & 0xFFFFFF;
        float wgt = __uint_as_float(p.y);
        ushort4 v = *(const ushort4*)&feat[(size_t)src * DFEAT + lane * 4];
        float x = wgt * bf2f(v.x);
        float y = wgt * bf2f(v.y);
        float z = wgt * bf2f(v.z);
        float u = wgt * bf2f(v.w);
        switch (low & 7) {                       // wave-uniform
            case 0: acc[0][0]+=x; acc[0][1]+=y; acc[0][2]+=z; acc[0][3]+=u; break;
            case 1: acc[1][0]+=x; acc[1][1]+=y; acc[1][2]+=z; acc[1][3]+=u; break;
            case 2: acc[2][0]+=x; acc[2][1]+=y; acc[2][2]+=z; acc[2][3]+=u; break;
            case 3: acc[3][0]+=x; acc[3][1]+=y; acc[3][2]+=z; acc[3][3]+=u; break;
            case 4: acc[4][0]+=x; acc[4][1]+=y; acc[4][2]+=z; acc[4][3]+=u; break;
            case 5: acc[5][0]+=x; acc[5][1]+=y; acc[5][2]+=z; acc[5][3]+=u; break;
            case 6: acc[6][0]+=x; acc[6][1]+=y; acc[6][2]+=z; acc[6][3]+=u; break;
            default: acc[7][0]+=x; acc[7][1]+=y; acc[7][2]+=z; acc[7][3]+=u; break;
        }
    }

    int rowbase = cs * NBATCH + b * BROWS + wave * 8;
    #pragma unroll
    for (int r = 0; r < 8; ++r) {
        ushort4 o;
        o.x = f2bf(acc[r][0]);
        o.y = f2bf(acc[r][1]);
        o.z = f2bf(acc[r][2]);
        o.w = f2bf(acc[r][3]);
        *(ushort4*)&agg[(size_t)(rowbase + r) * 256 + lane * 4] = o;
    }
}

// ============================================================================
// decoder stage 2
// ============================================================================
__global__ __launch_bounds__(256) void decoder_kernel(
    const float* __restrict__ t0, const float* __restrict__ t1,
    const u16* __restrict__ item_emb, const float* __restrict__ Wcomb,
    float* __restrict__ out)
{
    int wave = threadIdx.x >> 6;
    int lane = threadIdx.x & 63;
    int b = blockIdx.x * 4 + wave;
    const u16*   ie = item_emb + (size_t)b * 256;
    const float* p0 = t0 + (size_t)b * 256;
    const float* p1 = t1 + (size_t)b * 256;
    float s0 = 0.f, s1 = 0.f;
    #pragma unroll
    for (int j = lane; j < 256; j += 64) {
        float v = bf2f(ie[j]);
        s0 += p0[j] * v;
        s1 += p1[j] * v;
    }
    #pragma unroll
    for (int o = 32; o > 0; o >>= 1) {
        s0 += __shfl_down(s0, o);
        s1 += __shfl_down(s1, o);
    }
    if (lane == 0) {
        #pragma unroll
        for (int r = 0; r < NCLASS; ++r)
            out[b * NCLASS + r] = Wcomb[r * 2 + 0] * s0 + Wcomb[r * 2 + 1] * s1;
    }
}

// ============================================================================
// launch
// ============================================================================
extern "C" void kernel_launch(void* const* d_in, const int* in_sizes, int n_in,
                              void* d_out, int out_size, void* d_ws, size_t ws_size,
                              hipStream_t stream)
{
    const float* user_feat = (const float*)d_in[0];
    const float* item_feat = (const float*)d_in[1];
    const int*   user_idx  = (const int*)  d_in[2];
    const int*   item_idx  = (const int*)  d_in[3];
    const int*   u_src     = (const int*)  d_in[4];
    const int*   u_dst     = (const int*)  d_in[5];
    const float* u_w       = (const float*)d_in[6];
    const int*   i_src     = (const int*)  d_in[7];
    const int*   i_dst     = (const int*)  d_in[8];
    const float* i_w       = (const float*)d_in[9];
    const float* W_fu      = (const float*)d_in[10];
    const float* b_fu      = (const float*)d_in[11];
    const float* W_fi      = (const float*)d_in[12];
    const float* b_fi      = (const float*)d_in[13];
    const float* W_uc      = (const float*)d_in[14];
    const float* W_ic      = (const float*)d_in[15];
    const float* bn_fu     = (const float*)d_in[16];
    const float* bn_hu     = (const float*)d_in[17];
    const float* bn_fi     = (const float*)d_in[18];
    const float* bn_hi     = (const float*)d_in[19];
    const float* W2_fu     = (const float*)d_in[20];
    const float* W2_hu     = (const float*)d_in[21];
    const float* W2_fi     = (const float*)d_in[22];
    const float* W2_hi     = (const float*)d_in[23];
    const float* Wdec      = (const float*)d_in[24];
    const float* Wcomb     = (const float*)d_in[25];
    float* out = (float*)d_out;

    // ---- workspace layout --------------------------------------------------
    char* ws = (char*)d_ws;
    int*   bcounts    = (int*)  (ws + 0);            // 10*128 i32
    int*   boff       = (int*)  (ws + 8192);         // 10*129 i32
    int*   bcur       = (int*)  (ws + 16384);        // 10*128 i32
    uint2* part_ew    = (uint2*)(ws + 983040);       // 40 MB (dead after spmm)
    u16*   user_bf    = (u16*)  (ws + 40983040);     // 51.2 MB
    u16*   item_bf    = (u16*)  (ws + 92183040);     // 51.2 MB
    u16*   agg_bf     = (u16*)  (ws + 143383040);    // 41.9 MB (dead after hproj)
    u16*   wT         = (u16*)  (ws + 185326080);    // 2.1 MB
    // overlays on part region (live f-gemm..emb, after spmm):
    u16*   f_user_bf  = (u16*)  (ws + 983040);
    u16*   f_item_bf  = (u16*)  (ws + 5177344);
    u16*   h_user_bf  = (u16*)  (ws + 9371648);
    u16*   h_item_bf  = (u16*)  (ws + 19857408);
    // overlays on agg region (live emb..decoder, after hproj):
    float* t0         = (float*)(ws + 143383040);
    float* t1         = (float*)(ws + 151771648);
    u16*   user_emb   = (u16*)  (ws + 160160256);
    u16*   item_emb   = (u16*)  (ws + 164354560);

    // ---- 1. bucket CSR build ----------------------------------------------
    hipMemsetAsync(bcounts, 0, 10 * NBUCKET * sizeof(int), stream);
    hist_bucket<<<dim3(64, 10), 256, 0, stream>>>(u_dst, i_dst, bcounts);
    scan_bucket<<<10, NBUCKET, 0, stream>>>(bcounts, boff, bcur);
    partition_kernel<<<dim3(128, 10), 256, 0, stream>>>(
        u_src, u_dst, u_w, i_src, i_dst, i_w, bcur, part_ew);

    // ---- 2. prep conversions ----------------------------------------------
    cvt_feat<<<4096, 256, 0, stream>>>(user_feat, item_feat, user_bf, item_bf);
    cvt_wt<<<dim3(160, 9), 256, 0, stream>>>(W_fu, W_fi, W_uc, W_ic,
                                             W2_fu, W2_hu, W2_fi, W2_hi, Wdec, wT);

    // ---- 3. bucketed SpMM aggregation (register acc, no float atomics) -----
    spmm_scan<<<dim3(NBUCKET, 10), 512, 0, stream>>>(
        item_bf, user_bf, part_ew, boff, agg_bf);

    // ---- 4. f path ---------------------------------------------------------
    k_gemm_f<<<dim3(128, 4), 256, 0, stream>>>(user_bf, user_idx, wT + OFF_WFU,
                                               b_fu, bn_fu, f_user_bf);
    k_gemm_f<<<dim3(128, 4), 256, 0, stream>>>(item_bf, item_idx, wT + OFF_WFI,
                                               b_fi, bn_fi, f_item_bf);

    // ---- 5. h projection ---------------------------------------------------
    k_hproj<<<dim3(128, 2, 10), 256, 0, stream>>>(agg_bf, wT + OFF_WUC, wT + OFF_WIC,
                                                  bn_hu, bn_hi, h_user_bf, h_item_bf);

    // ---- 6. embeddings ------------------------------------------------------
    k_emb<<<dim3(128, 4), 256, 0, stream>>>(f_user_bf, h_user_bf,
                                            wT + OFF_W2FU, wT + OFF_W2HU, user_emb);
    k_emb<<<dim3(128, 4), 256, 0, stream>>>(f_item_bf, h_item_bf,
                                            wT + OFF_W2FI, wT + OFF_W2HI, item_emb);

    // ---- 7. decoder ---------------------------------------------------------
    k_dec<<<dim3(128, 4, 2), 256, 0, stream>>>(user_emb, wT + OFF_WDEC, t0, t1);
    decoder_kernel<<<NBATCH / 4, 256, 0, stream>>>(t0, t1, item_emb, Wcomb, out);
}

// Round 6
// 888.958 us; speedup vs baseline: 8.1926x; 2.6057x over previous
//
#include <hip/hip_runtime.h>
#include <cstdint>
#include <cstddef>

// Problem constants
#define NBATCH   8192
#define DFEAT    256
#define DCONV    128
#define NCLASS   5
#define NEDGE    500000
#define NUSERS   100000
#define BN_EPS   1e-3f
#define NBUCKET  128       // dst buckets of 64 rows each
#define BROWS    64
#define CAP      4608      // fixed bucket capacity (mean 3906, std 62 -> +11 sigma)

typedef unsigned short u16;
typedef short bf16x8_t __attribute__((ext_vector_type(8)));
typedef float f32x4_t  __attribute__((ext_vector_type(4)));

__device__ __forceinline__ u16 f2bf(float x) {
    unsigned u = __float_as_uint(x);
    u += 0x7FFF + ((u >> 16) & 1);
    return (u16)(u >> 16);
}
__device__ __forceinline__ float bf2f(u16 h) {
    return __uint_as_float(((unsigned)h) << 16);
}

// ============================================================================
// bf16 MFMA GEMM core: tile 64x64, block = 256 threads (4 waves), K-step 32.
// A row-major [M x K] bf16 (optionally row-gathered); BT row-major [N x K] bf16.
// LDS fragment-ordered -> all ds traffic conflict-free b128.
//   C/D: lane l, reg r -> row = (l>>4)*4 + r, col = l&15   (m89-verified)
// ============================================================================
__device__ __forceinline__ void mfma_tiles(
    const u16* __restrict__ A, int lda, const int* __restrict__ gather,
    const u16* __restrict__ BT, int K,
    int tileM, int tileN, u16* As, u16* Bs, f32x4_t acc[4])
{
    const int t    = threadIdx.x;
    const int rowi = t >> 2;
    const int kc   = t & 3;
    const int w    = t >> 6;
    const int lane = t & 63;

    int ar = gather ? gather[tileM + rowi] : (tileM + rowi);
    const u16* Ap = A  + (size_t)ar * lda + kc * 8;
    const u16* Bp = BT + (size_t)(tileN + rowi) * K + kc * 8;
    u16* Aw = As + (size_t)(((rowi >> 4) * 64) + (rowi & 15) + 16 * kc) * 8;
    u16* Bw = Bs + (size_t)(((rowi >> 4) * 64) + (rowi & 15) + 16 * kc) * 8;
    const u16* Ar = As + (size_t)(w * 64 + lane) * 8;

    for (int k0 = 0; k0 < K; k0 += 32) {
        __syncthreads();
        *(uint4*)Aw = *(const uint4*)(Ap + k0);
        *(uint4*)Bw = *(const uint4*)(Bp + k0);
        __syncthreads();
        bf16x8_t av = *(const bf16x8_t*)Ar;
        #pragma unroll
        for (int nb = 0; nb < 4; ++nb) {
            bf16x8_t bv = *(const bf16x8_t*)(Bs + (size_t)(nb * 64 + lane) * 8);
            acc[nb] = __builtin_amdgcn_mfma_f32_16x16x32_bf16(av, bv, acc[nb], 0, 0, 0);
        }
    }
}

__device__ __forceinline__ void epilogue(
    f32x4_t acc[4], int tileM, int tileN,
    const float* __restrict__ bias, const float* __restrict__ bn, int bn_ld,
    int relu, u16* __restrict__ out_bf, float* __restrict__ out_f32, int ldc)
{
    const int t = threadIdx.x, w = t >> 6, lane = t & 63;
    const int row0 = tileM + w * 16 + (lane >> 4) * 4;
    #pragma unroll
    for (int nb = 0; nb < 4; ++nb) {
        int col = tileN + nb * 16 + (lane & 15);
        float g = 1.f, be = 0.f, mu = 0.f, va = 1.f, bs = 0.f;
        if (bn)   { g = bn[col]; be = bn[bn_ld + col]; mu = bn[2 * bn_ld + col]; va = bn[3 * bn_ld + col]; }
        if (bias) bs = bias[col];
        #pragma unroll
        for (int r = 0; r < 4; ++r) {
            float x = acc[nb][r] + bs;
            if (bn)   x = g * (x - mu) * rsqrtf(va + BN_EPS) + be;
            if (relu) x = fmaxf(x, 0.f);
            size_t o = (size_t)(row0 + r) * ldc + col;
            if (out_bf) out_bf[o] = f2bf(x);
            else        out_f32[o] = x;
        }
    }
}

// f path, fused user(z=0)/item(z=1)
__global__ __launch_bounds__(256) void k_gemm_f(
    const u16* __restrict__ ubf, const u16* __restrict__ ibf,
    const int* __restrict__ uidx, const int* __restrict__ iidx,
    const u16* __restrict__ WTu, const u16* __restrict__ WTi,
    const float* __restrict__ bu, const float* __restrict__ bi,
    const float* __restrict__ bnu, const float* __restrict__ bni,
    u16* __restrict__ outu, u16* __restrict__ outi)
{
    __shared__ __align__(16) u16 As[2048], Bs[2048];
    f32x4_t z4 = {0.f, 0.f, 0.f, 0.f};
    f32x4_t acc[4] = {z4, z4, z4, z4};
    int z = blockIdx.z;
    const u16* feat = z ? ibf : ubf;
    const int* idx  = z ? iidx : uidx;
    const u16* WT   = z ? WTi : WTu;
    const float* bias = z ? bi : bu;
    const float* bn   = z ? bni : bnu;
    u16* out = z ? outi : outu;
    int tileM = blockIdx.x * 64, tileN = blockIdx.y * 64;
    mfma_tiles(feat, 256, idx, WT, 256, tileM, tileN, As, Bs, acc);
    epilogue(acc, tileM, tileN, bias, bn, 256, 1, out, nullptr, 256);
}

__global__ __launch_bounds__(256) void k_hproj(
    const u16* __restrict__ agg, const u16* __restrict__ WucT, const u16* __restrict__ WicT,
    const float* __restrict__ bn_hu, const float* __restrict__ bn_hi,
    u16* __restrict__ h_user, u16* __restrict__ h_item)
{
    __shared__ __align__(16) u16 As[2048], Bs[2048];
    f32x4_t z4 = {0.f, 0.f, 0.f, 0.f};
    f32x4_t acc[4] = {z4, z4, z4, z4};
    int cs = blockIdx.z, c = cs % NCLASS, side = cs / NCLASS;
    const u16* A  = agg + (size_t)cs * NBATCH * DFEAT;
    const u16* BT = (side ? WicT : WucT) + (size_t)c * DCONV * DFEAT;
    const float* bn = (side ? bn_hi : bn_hu) + c * DCONV;
    u16* out = (side ? h_item : h_user) + c * DCONV;
    int tileM = blockIdx.x * 64, tileN = blockIdx.y * 64;
    mfma_tiles(A, 256, nullptr, BT, 256, tileM, tileN, As, Bs, acc);
    epilogue(acc, tileM, tileN, nullptr, bn, NCLASS * DCONV, 1, out, nullptr, NCLASS * DCONV);
}

// embedding, fused user(z=0)/item(z=1), K = 256 + 640
__global__ __launch_bounds__(256) void k_emb(
    const u16* __restrict__ fu, const u16* __restrict__ fi,
    const u16* __restrict__ hu, const u16* __restrict__ hi,
    const u16* __restrict__ W2fTu, const u16* __restrict__ W2hTu,
    const u16* __restrict__ W2fTi, const u16* __restrict__ W2hTi,
    u16* __restrict__ embu, u16* __restrict__ embi)
{
    __shared__ __align__(16) u16 As[2048], Bs[2048];
    f32x4_t z4 = {0.f, 0.f, 0.f, 0.f};
    f32x4_t acc[4] = {z4, z4, z4, z4};
    int z = blockIdx.z;
    const u16* fbf  = z ? fi : fu;
    const u16* hbf  = z ? hi : hu;
    const u16* W2fT = z ? W2fTi : W2fTu;
    const u16* W2hT = z ? W2hTi : W2hTu;
    u16* emb = z ? embi : embu;
    int tileM = blockIdx.x * 64, tileN = blockIdx.y * 64;
    mfma_tiles(fbf, 256, nullptr, W2fT, 256, tileM, tileN, As, Bs, acc);
    mfma_tiles(hbf, NCLASS * DCONV, nullptr, W2hT, NCLASS * DCONV, tileM, tileN, As, Bs, acc);
    epilogue(acc, tileM, tileN, nullptr, nullptr, 0, 1, emb, nullptr, 256);
}

__global__ __launch_bounds__(256) void k_dec(
    const u16* __restrict__ emb, const u16* __restrict__ WdecT,
    float* __restrict__ t0, float* __restrict__ t1)
{
    __shared__ __align__(16) u16 As[2048], Bs[2048];
    f32x4_t z4 = {0.f, 0.f, 0.f, 0.f};
    f32x4_t acc[4] = {z4, z4, z4, z4};
    int zi = blockIdx.z;
    const u16* BT = WdecT + (size_t)zi * 256 * 256;
    float* out = zi ? t1 : t0;
    int tileM = blockIdx.x * 64, tileN = blockIdx.y * 64;
    mfma_tiles(emb, 256, nullptr, BT, 256, tileM, tileN, As, Bs, acc);
    epilogue(acc, tileM, tileN, nullptr, nullptr, 0, 0, nullptr, out, 256);
}

// ============================================================================
// prep conversions
// ============================================================================
__global__ __launch_bounds__(256) void cvt_feat(
    const float* __restrict__ uf, const float* __restrict__ itf,
    u16* __restrict__ ubf, u16* __restrict__ ibf)
{
    const size_t n4 = (size_t)NUSERS * DFEAT / 4;
    for (size_t i = (size_t)blockIdx.x * 256 + threadIdx.x; i < 2 * n4;
         i += (size_t)gridDim.x * 256) {
        bool u = i < n4;
        size_t j = u ? i : i - n4;
        float4 v = u ? ((const float4*)uf)[j] : ((const float4*)itf)[j];
        ushort4 o;
        o.x = f2bf(v.x); o.y = f2bf(v.y); o.z = f2bf(v.z); o.w = f2bf(v.w);
        ((ushort4*)(u ? ubf : ibf))[j] = o;
    }
}

#define OFF_WFU   0
#define OFF_WFI   65536
#define OFF_WUC   131072
#define OFF_WIC   294912
#define OFF_W2FU  458752
#define OFF_W2HU  524288
#define OFF_W2FI  688128
#define OFF_W2HI  753664
#define OFF_WDEC  917504

__global__ __launch_bounds__(256) void cvt_wt(
    const float* __restrict__ Wfu, const float* __restrict__ Wfi,
    const float* __restrict__ Wuc, const float* __restrict__ Wic,
    const float* __restrict__ W2fu, const float* __restrict__ W2hu,
    const float* __restrict__ W2fi, const float* __restrict__ W2hi,
    const float* __restrict__ Wdec, u16* __restrict__ wT)
{
    const float* in; u16* out; int K, N, B;
    switch (blockIdx.y) {
        case 0: in = Wfu;  out = wT + OFF_WFU;  K = 256; N = 256; B = 1; break;
        case 1: in = Wfi;  out = wT + OFF_WFI;  K = 256; N = 256; B = 1; break;
        case 2: in = Wuc;  out = wT + OFF_WUC;  K = 256; N = 128; B = 5; break;
        case 3: in = Wic;  out = wT + OFF_WIC;  K = 256; N = 128; B = 5; break;
        case 4: in = W2fu; out = wT + OFF_W2FU; K = 256; N = 256; B = 1; break;
        case 5: in = W2hu; out = wT + OFF_W2HU; K = 640; N = 256; B = 1; break;
        case 6: in = W2fi; out = wT + OFF_W2FI; K = 256; N = 256; B = 1; break;
        case 7: in = W2hi; out = wT + OFF_W2HI; K = 640; N = 256; B = 1; break;
        default: in = Wdec; out = wT + OFF_WDEC; K = 256; N = 256; B = 2; break;
    }
    int total = B * K * N;
    for (int idx = blockIdx.x * 256 + threadIdx.x; idx < total; idx += gridDim.x * 256) {
        int b = idx / (K * N);
        int r = idx - b * K * N;
        int n = r / K;
        int k = r - n * K;
        out[idx] = f2bf(in[(size_t)(b * K + k) * N + n]);
    }
}

// ============================================================================
// Bucketed graph aggregation, fixed-capacity bucket regions (CAP edges each).
// init_bcur: bucket write cursors start at region bases (b*CAP within cs).
// partition: two-level. Per-block LDS histogram of its ~3.9K-edge chunk ->
//            ONE global atomicAdd per (block,bucket) to reserve a range ->
//            per-edge placement via native LDS int cursors. 16K global
//            atomics total (vs 5M in R3/R5). Overflow-guarded (drop, can't
//            happen for CAP=+11sigma).
// spmm_sorted: block per (bucket, cs), 512 thr. In-LDS counting sort of the
//            bucket's edges by dst-low6 (u16 permutation, native int LDS
//            atomics), then wave w processes rows [8w,8w+8) with contiguous
//            edge lists: each edge read ONCE, 512B coalesced feature gather,
//            register fp32 accumulate, unroll-4 for gather ILP.
//            No float atomics anywhere (gfx950 LDS float atomicAdd = CAS
//            loop, R4's 6.4ms lesson). No 8x scan (R5's 1.5ms lesson).
// ============================================================================
__global__ __launch_bounds__(256) void init_bcur(int* __restrict__ bcur)
{
    int i = blockIdx.x * 256 + threadIdx.x;
    if (i < 10 * NBUCKET) bcur[i] = (i & (NBUCKET - 1)) * CAP;
}

__global__ __launch_bounds__(256) void partition_kernel(
    const int* __restrict__ u_src, const int* __restrict__ u_dst, const float* __restrict__ u_w,
    const int* __restrict__ i_src, const int* __restrict__ i_dst, const float* __restrict__ i_w,
    int* __restrict__ bcur, uint2* __restrict__ part)
{
    __shared__ int hist[NBUCKET];
    __shared__ int cur[NBUCKET];
    int cs = blockIdx.y;
    const int* srcp; const int* dstp; const float* wp;
    if (cs < NCLASS) {
        srcp = u_src + (size_t)cs * NEDGE;
        dstp = u_dst + (size_t)cs * NEDGE;
        wp   = u_w   + (size_t)cs * NEDGE;
    } else {
        int c = cs - NCLASS;
        srcp = i_src + (size_t)c * NEDGE;
        dstp = i_dst + (size_t)c * NEDGE;
        wp   = i_w   + (size_t)c * NEDGE;
    }
    int lo_e = (int)(((long long)blockIdx.x * NEDGE) / gridDim.x);
    int hi_e = (int)(((long long)(blockIdx.x + 1) * NEDGE) / gridDim.x);

    for (int i = threadIdx.x; i < NBUCKET; i += 256) hist[i] = 0;
    __syncthreads();
    for (int e = lo_e + threadIdx.x; e < hi_e; e += 256)
        atomicAdd(&hist[dstp[e] >> 6], 1);           // native LDS int atomic
    __syncthreads();
    for (int i = threadIdx.x; i < NBUCKET; i += 256)
        cur[i] = atomicAdd(&bcur[cs * NBUCKET + i], hist[i]);  // one per (block,bucket)
    __syncthreads();
    uint2* out = part + (size_t)cs * NBUCKET * CAP;
    for (int e = lo_e + threadIdx.x; e < hi_e; e += 256) {
        int dst = dstp[e];
        int bkt = dst >> 6;
        int pos = atomicAdd(&cur[bkt], 1);           // native LDS int atomic
        if (pos < bkt * CAP + CAP)                   // overflow guard
            out[pos] = make_uint2((unsigned)srcp[e] | ((unsigned)(dst & 63) << 24),
                                  __float_as_uint(wp[e]));
    }
}

__global__ __launch_bounds__(512) void spmm_sorted(
    const u16* __restrict__ item_bf, const u16* __restrict__ user_bf,
    const uint2* __restrict__ part, const int* __restrict__ bcur,
    u16* __restrict__ agg)
{
    __shared__ int bin_cnt[BROWS];
    __shared__ int bin_off[BROWS + 1];
    __shared__ int bin_cur[BROWS];
    __shared__ u16 perm[CAP];
    int b  = blockIdx.x;
    int cs = blockIdx.y;
    const u16* feat = (cs < NCLASS) ? item_bf : user_bf;
    int n = bcur[cs * NBUCKET + b] - b * CAP;
    if (n > CAP) n = CAP;
    const uint2* ew = part + ((size_t)cs * NBUCKET + b) * CAP;
    int tid = threadIdx.x, wave = tid >> 6, lane = tid & 63;

    if (tid < BROWS) bin_cnt[tid] = 0;
    __syncthreads();
    for (int e = tid; e < n; e += 512)
        atomicAdd(&bin_cnt[ew[e].x >> 24], 1);       // native LDS int atomic
    __syncthreads();
    if (tid < 64) {                                  // wave-0 shfl inclusive scan
        int c = bin_cnt[tid];
        int v = c;
        #pragma unroll
        for (int o = 1; o < 64; o <<= 1) {
            int u = __shfl_up(v, o);
            if (lane >= o) v += u;
        }
        bin_off[tid + 1] = v;
        bin_cur[tid] = v - c;
        if (tid == 0) bin_off[0] = 0;
    }
    __syncthreads();
    for (int e = tid; e < n; e += 512) {
        int low = ew[e].x >> 24;
        int pos = atomicAdd(&bin_cur[low], 1);
        perm[pos] = (u16)e;
    }
    __syncthreads();

    int rowbase = cs * NBATCH + b * BROWS;
    #pragma unroll
    for (int r0 = 0; r0 < 8; ++r0) {
        int r = wave * 8 + r0;
        int j0 = bin_off[r], j1 = bin_off[r + 1];
        float ax = 0.f, ay = 0.f, az = 0.f, aw = 0.f;
        int j = j0;
        for (; j + 3 < j1; j += 4) {
            int l0 = perm[j], l1 = perm[j + 1], l2 = perm[j + 2], l3 = perm[j + 3];
            uint2 p0 = ew[l0], p1 = ew[l1], p2 = ew[l2], p3 = ew[l3];
            ushort4 v0 = *(const ushort4*)&feat[(size_t)(p0.x & 0xFFFFFF) * DFEAT + lane * 4];
            ushort4 v1 = *(const ushort4*)&feat[(size_t)(p1.x & 0xFFFFFF) * DFEAT + lane * 4];
            ushort4 v2 = *(const ushort4*)&feat[(size_t)(p2.x & 0xFFFFFF) * DFEAT + lane * 4];
            ushort4 v3 = *(const ushort4*)&feat[(size_t)(p3.x & 0xFFFFFF) * DFEAT + lane * 4];
            float w0 = __uint_as_float(p0.y), w1 = __uint_as_float(p1.y);
            float w2 = __uint_as_float(p2.y), w3 = __uint_as_float(p3.y);
            ax += w0 * bf2f(v0.x) + w1 * bf2f(v1.x) + w2 * bf2f(v2.x) + w3 * bf2f(v3.x);
            ay += w0 * bf2f(v0.y) + w1 * bf2f(v1.y) + w2 * bf2f(v2.y) + w3 * bf2f(v3.y);
            az += w0 * bf2f(v0.z) + w1 * bf2f(v1.z) + w2 * bf2f(v2.z) + w3 * bf2f(v3.z);
            aw += w0 * bf2f(v0.w) + w1 * bf2f(v1.w) + w2 * bf2f(v2.w) + w3 * bf2f(v3.w);
        }
        for (; j < j1; ++j) {
            int l0 = perm[j];
            uint2 p0 = ew[l0];
            ushort4 v0 = *(const ushort4*)&feat[(size_t)(p0.x & 0xFFFFFF) * DFEAT + lane * 4];
            float w0 = __uint_as_float(p0.y);
            ax += w0 * bf2f(v0.x);
            ay += w0 * bf2f(v0.y);
            az += w0 * bf2f(v0.z);
            aw += w0 * bf2f(v0.w);
        }
        ushort4 o4;
        o4.x = f2bf(ax); o4.y = f2bf(ay); o4.z = f2bf(az); o4.w = f2bf(aw);
        *(ushort4*)&agg[(size_t)(rowbase + r) * 256 + lane * 4] = o4;
    }
}

// ============================================================================
// decoder stage 2
// ============================================================================
__global__ __launch_bounds__(256) void decoder_kernel(
    const float* __restrict__ t0, const float* __restrict__ t1,
    const u16* __restrict__ item_emb, const float* __restrict__ Wcomb,
    float* __restrict__ out)
{
    int wave = threadIdx.x >> 6;
    int lane = threadIdx.x & 63;
    int b = blockIdx.x * 4 + wave;
    const u16*   ie = item_emb + (size_t)b * 256;
    const float* p0 = t0 + (size_t)b * 256;
    const float* p1 = t1 + (size_t)b * 256;
    float s0 = 0.f, s1 = 0.f;
    #pragma unroll
    for (int j = lane; j < 256; j += 64) {
        float v = bf2f(ie[j]);
        s0 += p0[j] * v;
        s1 += p1[j] * v;
    }
    #pragma unroll
    for (int o = 32; o > 0; o >>= 1) {
        s0 += __shfl_down(s0, o);
        s1 += __shfl_down(s1, o);
    }
    if (lane == 0) {
        #pragma unroll
        for (int r = 0; r < NCLASS; ++r)
            out[b * NCLASS + r] = Wcomb[r * 2 + 0] * s0 + Wcomb[r * 2 + 1] * s1;
    }
}

// ============================================================================
// launch
// ============================================================================
extern "C" void kernel_launch(void* const* d_in, const int* in_sizes, int n_in,
                              void* d_out, int out_size, void* d_ws, size_t ws_size,
                              hipStream_t stream)
{
    const float* user_feat = (const float*)d_in[0];
    const float* item_feat = (const float*)d_in[1];
    const int*   user_idx  = (const int*)  d_in[2];
    const int*   item_idx  = (const int*)  d_in[3];
    const int*   u_src     = (const int*)  d_in[4];
    const int*   u_dst     = (const int*)  d_in[5];
    const float* u_w       = (const float*)d_in[6];
    const int*   i_src     = (const int*)  d_in[7];
    const int*   i_dst     = (const int*)  d_in[8];
    const float* i_w       = (const float*)d_in[9];
    const float* W_fu      = (const float*)d_in[10];
    const float* b_fu      = (const float*)d_in[11];
    const float* W_fi      = (const float*)d_in[12];
    const float* b_fi      = (const float*)d_in[13];
    const float* W_uc      = (const float*)d_in[14];
    const float* W_ic      = (const float*)d_in[15];
    const float* bn_fu     = (const float*)d_in[16];
    const float* bn_hu     = (const float*)d_in[17];
    const float* bn_fi     = (const float*)d_in[18];
    const float* bn_hi     = (const float*)d_in[19];
    const float* W2_fu     = (const float*)d_in[20];
    const float* W2_hu     = (const float*)d_in[21];
    const float* W2_fi     = (const float*)d_in[22];
    const float* W2_hi     = (const float*)d_in[23];
    const float* Wdec      = (const float*)d_in[24];
    const float* Wcomb     = (const float*)d_in[25];
    float* out = (float*)d_out;

    // ---- workspace layout (193.7 MB; harness ws >= 200.4 MB proven R1) ----
    char* ws = (char*)d_ws;
    int*   bcur       = (int*)  (ws + 0);            // 1280 i32
    uint2* part_ew    = (uint2*)(ws + 65536);        // 10*128*4608*8 = 47.2 MB
    u16*   user_bf    = (u16*)  (ws + 47251456);     // 51.2 MB
    u16*   item_bf    = (u16*)  (ws + 98451456);     // 51.2 MB
    u16*   agg_bf     = (u16*)  (ws + 149651456);    // 41.9 MB (dead after hproj)
    u16*   wT         = (u16*)  (ws + 191594496);    // 2.1 MB -> end 193691648
    // overlays on part region (live f-gemm..emb, after spmm):
    u16*   f_user_bf  = (u16*)  (ws + 65536);        // 4.2 MB
    u16*   f_item_bf  = (u16*)  (ws + 4259840);      // 4.2 MB
    u16*   h_user_bf  = (u16*)  (ws + 8454144);      // 10.5 MB
    u16*   h_item_bf  = (u16*)  (ws + 18939904);     // 10.5 MB
    // overlays on agg region (live emb..decoder, after hproj):
    float* t0         = (float*)(ws + 149651456);    // 8.4 MB
    float* t1         = (float*)(ws + 158040064);    // 8.4 MB
    u16*   user_emb   = (u16*)  (ws + 166428672);    // 4.2 MB
    u16*   item_emb   = (u16*)  (ws + 170622976);    // 4.2 MB

    // ---- 1. bucket partition (fixed-capacity regions) ----------------------
    init_bcur<<<5, 256, 0, stream>>>(bcur);
    partition_kernel<<<dim3(128, 10), 256, 0, stream>>>(
        u_src, u_dst, u_w, i_src, i_dst, i_w, bcur, part_ew);

    // ---- 2. prep conversions ----------------------------------------------
    cvt_feat<<<4096, 256, 0, stream>>>(user_feat, item_feat, user_bf, item_bf);
    cvt_wt<<<dim3(160, 9), 256, 0, stream>>>(W_fu, W_fi, W_uc, W_ic,
                                             W2_fu, W2_hu, W2_fi, W2_hi, Wdec, wT);

    // ---- 3. SpMM: in-LDS counting sort + single-pass register accumulate ---
    spmm_sorted<<<dim3(NBUCKET, 10), 512, 0, stream>>>(
        item_bf, user_bf, part_ew, bcur, agg_bf);

    // ---- 4. f path (fused user/item) ---------------------------------------
    k_gemm_f<<<dim3(128, 4, 2), 256, 0, stream>>>(
        user_bf, item_bf, user_idx, item_idx, wT + OFF_WFU, wT + OFF_WFI,
        b_fu, b_fi, bn_fu, bn_fi, f_user_bf, f_item_bf);

    // ---- 5. h projection ---------------------------------------------------
    k_hproj<<<dim3(128, 2, 10), 256, 0, stream>>>(agg_bf, wT + OFF_WUC, wT + OFF_WIC,
                                                  bn_hu, bn_hi, h_user_bf, h_item_bf);

    // ---- 6. embeddings (fused user/item; agg region now dead) --------------
    k_emb<<<dim3(128, 4, 2), 256, 0, stream>>>(
        f_user_bf, f_item_bf, h_user_bf, h_item_bf,
        wT + OFF_W2FU, wT + OFF_W2HU, wT + OFF_W2FI, wT + OFF_W2HI,
        user_emb, item_emb);

    // ---- 7. decoder ---------------------------------------------------------
    k_dec<<<dim3(128, 4, 2), 256, 0, stream>>>(user_emb, wT + OFF_WDEC, t0, t1);
    decoder_kernel<<<NBATCH / 4, 256, 0, stream>>>(t0, t1, item_emb, Wcomb, out);
}